// Round 19
// baseline (478.022 us; speedup 1.0000x reference)
//
#include <hip/hip_runtime.h>
#include <hip/hip_fp16.h>

#define N_NODES 100000
#define N_EDGES 1600000
#define D 64
#define N_GRAPHS 64
#define NBLK ((N_NODES + 255) / 256)   // 391 scan blocks
#define WTS 68                         // WT row stride (floats): conflict-free

// ---------------- packed degree + count: ONE uint64 atomic per edge ---------
// deg64[d] += (1<<40) | round(ew * 2^20): upper bits = edge count, low 40 =
// fixed-point weight sum (max sum ~60 << 2^20 capacity; err <= 5e-7/edge).
__global__ void k_count_deg(const int4* __restrict__ dst4,
                            const float4* __restrict__ ew4,
                            unsigned long long* __restrict__ deg64) {
    int e4 = blockIdx.x * blockDim.x + threadIdx.x;
    if (e4 < N_EDGES / 4) {
        int4   d = dst4[e4];
        float4 w = ew4[e4];
        const float s = 1048576.0f;   // 2^20
        atomicAdd(&deg64[d.x], (1ULL << 40) + (unsigned long long)(w.x * s + 0.5f));
        atomicAdd(&deg64[d.y], (1ULL << 40) + (unsigned long long)(w.y * s + 0.5f));
        atomicAdd(&deg64[d.z], (1ULL << 40) + (unsigned long long)(w.z * s + 0.5f));
        atomicAdd(&deg64[d.w], (1ULL << 40) + (unsigned long long)(w.w * s + 0.5f));
    }
}

// ---------------- unpack dinv + exclusive scan of cnt -> partial ------------
__global__ void k_scan1(const unsigned long long* __restrict__ deg64,
                        int* __restrict__ partial, int* __restrict__ bsums,
                        float* __restrict__ dinv) {
    int t = threadIdx.x, b = blockIdx.x, i = b * 256 + t;
    int v = 0;
    if (i < N_NODES) {
        unsigned long long pk = deg64[i];
        v = (int)(pk >> 40);
        float degf = (float)(pk & ((1ULL << 40) - 1)) * (1.0f / 1048576.0f);
        dinv[i] = rsqrtf(degf + 1.0f);   // + self-loop weight 1
    }
    int incl = v;
    int lane = t & 63;
#pragma unroll
    for (int off = 1; off < 64; off <<= 1) {
        int u = __shfl_up(incl, off);
        if (lane >= off) incl += u;
    }
    __shared__ int wsum[4];
    int w = t >> 6;
    if (lane == 63) wsum[w] = incl;
    __syncthreads();
    int add = 0;
    for (int k = 0; k < w; ++k) add += wsum[k];
    incl += add;
    if (i < N_NODES) partial[i] = incl;
    if (t == 255) bsums[b] = incl;
}

__global__ void k_scan2(int* __restrict__ bsums) {
    __shared__ int s[512];
    int t = threadIdx.x;
    s[t] = (t < NBLK) ? bsums[t] : 0;
    __syncthreads();
    for (int off = 1; off < 512; off <<= 1) {
        int u = (t >= off) ? s[t - off] : 0;
        __syncthreads();
        s[t] += u;
        __syncthreads();
    }
    if (t < NBLK) bsums[t] = (t == 0) ? 0 : s[t - 1];  // exclusive
}

// writes rowptr, cursor AND a separate cnt array (so k_layer's row setup is
// two INDEPENDENT scalar loads, not a serial rowptr[i]/rowptr[i+1] chain)
__global__ void k_scan3(const int* __restrict__ partial,
                        const unsigned long long* __restrict__ deg64,
                        const int* __restrict__ bsums, int* __restrict__ rowptr,
                        int* __restrict__ cursor, int* __restrict__ cnt) {
    int i = blockIdx.x * 256 + threadIdx.x;
    if (i < N_NODES) {
        int c = (int)(deg64[i] >> 40);
        int excl = partial[i] - c + bsums[blockIdx.x];
        rowptr[i] = excl;
        cursor[i] = excl;
        cnt[i] = c;
    }
}

// ---------------- scatter edges into CSR (src, norm), 4 edges/thread --------
__global__ void k_scatter(const int4* __restrict__ src4, const int4* __restrict__ dst4,
                          const float4* __restrict__ ew4, const float* __restrict__ dinv,
                          int* __restrict__ cursor, float2* __restrict__ csr) {
    int e4 = blockIdx.x * blockDim.x + threadIdx.x;
    if (e4 < N_EDGES / 4) {
        int4   s = src4[e4];
        int4   d = dst4[e4];
        float4 w = ew4[e4];
        float n0 = dinv[s.x] * w.x * dinv[d.x];   // dinv 400KB: L2-resident
        float n1 = dinv[s.y] * w.y * dinv[d.y];
        float n2 = dinv[s.z] * w.z * dinv[d.z];
        float n3 = dinv[s.w] * w.w * dinv[d.w];
        int p0 = atomicAdd(&cursor[d.x], 1);
        int p1 = atomicAdd(&cursor[d.y], 1);
        int p2 = atomicAdd(&cursor[d.z], 1);
        int p3 = atomicAdd(&cursor[d.w], 1);
        csr[p0] = make_float2(__int_as_float(s.x), n0);
        csr[p1] = make_float2(__int_as_float(s.y), n1);
        csr[p2] = make_float2(__int_as_float(s.z), n2);
        csr[p3] = make_float2(__int_as_float(s.w), n3);
    }
}

// ---------------- x -> fp16 table [N][64] ----------------
__global__ void k_half(const float* __restrict__ x, __half* __restrict__ xh) {
    int i = blockIdx.x * blockDim.x + threadIdx.x;
    const int total = N_NODES * D / 4;
    const int stride = gridDim.x * blockDim.x;
    const float4* x4 = (const float4*)x;
    __half2* xh2 = (__half2*)xh;
    for (; i < total; i += stride) {
        float4 v = x4[i];
        xh2[2 * i + 0] = __floats2half2_rn(v.x, v.y);
        xh2[2 * i + 1] = __floats2half2_rn(v.z, v.w);
    }
}

// ---------------- fused layer: fp16 table + float4-grouped gathers ----------
// r16 proven kernel EXACTLY (independent rowptr/cnt row setup).
// lane = (slot in [0,4))*16 + q. Per 16-edge pass: 1 csr load + 8 shfl +
// 4 uint2 gathers (each covers 4 fp16 rows, 512 B). Slot-fold: 8 shfl_xor.
// GEMM f32 (transposed-W LDS, stride 68).
// LAYER==1: store row as fp16 (next table). LAYER==2: f32 pool-atomicAdd.
template <int LAYER>
__global__ __launch_bounds__(256) void k_layer(
        const __half* __restrict__ in, const float* __restrict__ W,
        const float* __restrict__ bias, const float* __restrict__ dinv,
        const int* __restrict__ rowptr, const int* __restrict__ cnt,
        const float2* __restrict__ csr, const int* __restrict__ batch,
        __half* __restrict__ outh, float* __restrict__ outf) {
    __shared__ float WTs[D * WTS];       // 17408 B transposed W
    __shared__ float aw[4][D];           // per-wave row staging
    __shared__ float bs[D];

    {   // stage W transposed: WTs[c*WTS + k] = W[k*D + c]
        int t = threadIdx.x;
#pragma unroll
        for (int i = 0; i < 16; ++i) {
            int idx = t + i * 256;
            int k = idx >> 6, c = idx & 63;
            WTs[c * WTS + k] = W[idx];
        }
        if (t < D) bs[t] = bias[t];
    }
    __syncthreads();

    const int lane = threadIdx.x & 63;
    const int wid  = threadIdx.x >> 6;
    const int slot = lane >> 4;          // 0..3
    const int q    = lane & 15;          // 0..15
    float* awm = aw[wid];
    const float bl = bs[lane];
    const uint2* in2 = (const uint2*)in; // row i = in2[i*16 .. i*16+15]

    int gw = (blockIdx.x * blockDim.x + threadIdx.x) >> 6;
    const int tw = (gridDim.x * blockDim.x) >> 6;

    for (int row = gw; row < N_NODES; row += tw) {
        const int st = __builtin_amdgcn_readfirstlane(rowptr[row]);
        const int dg = __builtin_amdgcn_readfirstlane(cnt[row]);
        const int cl = dg > 0 ? dg - 1 : 0;   // clamp index (safe for dg==0)

        float4 acc = make_float4(0.f, 0.f, 0.f, 0.f);
        {   // self-loop on slot 0
            if (slot == 0) {
                float di = dinv[row];
                float d2 = di * di;
                uint2 v = in2[row * 16 + q];
                float2 f0 = __half22float2(*(__half2*)&v.x);
                float2 f1 = __half22float2(*(__half2*)&v.y);
                acc.x = f0.x * d2; acc.y = f0.y * d2;
                acc.z = f1.x * d2; acc.w = f1.y * d2;
            }
        }

        for (int j = 0; j < dg; j += 16) {
            // one per-lane csr load covers 16 edges (4x slot redundancy)
            int ie = j + q;
            float2 c = csr[st + (ie < cl ? ie : cl)];
            // distribute: slot handles edges j+4k+slot (entry in lane 4k+slot)
            float sx0 = __shfl(c.x, 4 * 0 + slot);
            float wv0 = __shfl(c.y, 4 * 0 + slot);
            float sx1 = __shfl(c.x, 4 * 1 + slot);
            float wv1 = __shfl(c.y, 4 * 1 + slot);
            float sx2 = __shfl(c.x, 4 * 2 + slot);
            float wv2 = __shfl(c.y, 4 * 2 + slot);
            float sx3 = __shfl(c.x, 4 * 3 + slot);
            float wv3 = __shfl(c.y, 4 * 3 + slot);
            wv0 = (j + 0  + slot < dg) ? wv0 : 0.f;
            wv1 = (j + 4  + slot < dg) ? wv1 : 0.f;
            wv2 = (j + 8  + slot < dg) ? wv2 : 0.f;
            wv3 = (j + 12 + slot < dg) ? wv3 : 0.f;
            int i0 = __float_as_int(sx0);
            int i1 = __float_as_int(sx1);
            int i2 = __float_as_int(sx2);
            int i3 = __float_as_int(sx3);
            // 4 uint2 gathers: each instruction covers 4 fp16 rows (512 B)
            uint2 v0 = in2[i0 * 16 + q];
            uint2 v1 = in2[i1 * 16 + q];
            uint2 v2 = in2[i2 * 16 + q];
            uint2 v3 = in2[i3 * 16 + q];
            {
                float2 f0 = __half22float2(*(__half2*)&v0.x);
                float2 f1 = __half22float2(*(__half2*)&v0.y);
                acc.x = fmaf(f0.x, wv0, acc.x); acc.y = fmaf(f0.y, wv0, acc.y);
                acc.z = fmaf(f1.x, wv0, acc.z); acc.w = fmaf(f1.y, wv0, acc.w);
            }
            {
                float2 f0 = __half22float2(*(__half2*)&v1.x);
                float2 f1 = __half22float2(*(__half2*)&v1.y);
                acc.x = fmaf(f0.x, wv1, acc.x); acc.y = fmaf(f0.y, wv1, acc.y);
                acc.z = fmaf(f1.x, wv1, acc.z); acc.w = fmaf(f1.y, wv1, acc.w);
            }
            {
                float2 f0 = __half22float2(*(__half2*)&v2.x);
                float2 f1 = __half22float2(*(__half2*)&v2.y);
                acc.x = fmaf(f0.x, wv2, acc.x); acc.y = fmaf(f0.y, wv2, acc.y);
                acc.z = fmaf(f1.x, wv2, acc.z); acc.w = fmaf(f1.y, wv2, acc.w);
            }
            {
                float2 f0 = __half22float2(*(__half2*)&v3.x);
                float2 f1 = __half22float2(*(__half2*)&v3.y);
                acc.x = fmaf(f0.x, wv3, acc.x); acc.y = fmaf(f0.y, wv3, acc.y);
                acc.z = fmaf(f1.x, wv3, acc.z); acc.w = fmaf(f1.y, wv3, acc.w);
            }
        }

        // fold the 4 slots (same q): slot 0 ends with the row
        acc.x += __shfl_xor(acc.x, 16); acc.y += __shfl_xor(acc.y, 16);
        acc.z += __shfl_xor(acc.z, 16); acc.w += __shfl_xor(acc.w, 16);
        acc.x += __shfl_xor(acc.x, 32); acc.y += __shfl_xor(acc.y, 32);
        acc.z += __shfl_xor(acc.z, 32); acc.w += __shfl_xor(acc.w, 32);
        if (slot == 0) *(float4*)&awm[q * 4] = acc;
        // same-wave LDS RAW: in-order LDS pipe, no barrier needed

        // ---- GEMM: r[lane] = sum_k aw[k] * W[k][lane] ----
        float r0 = 0.f, r1 = 0.f, r2 = 0.f, r3 = 0.f;
#pragma unroll
        for (int t = 0; t < 16; ++t) {
            float4 a = *(const float4*)&awm[t * 4];                // broadcast
            float4 w = *(const float4*)&WTs[lane * WTS + t * 4];   // conflict-free
            r0 = fmaf(a.x, w.x, r0);
            r1 = fmaf(a.y, w.y, r1);
            r2 = fmaf(a.z, w.z, r2);
            r3 = fmaf(a.w, w.w, r3);
        }
        float r = fmaxf((r0 + r1) + (r2 + r3) + bl, 0.f);

        if (LAYER == 1) {
            outh[row * D + lane] = __float2half_rn(r);   // fp16 table for L2
        } else {
            atomicAdd(&outf[batch[row] * D + lane], r);
        }
    }
}

// ---------------- finalize pool: divide by per-graph node count ----------------
__global__ void k_finalize(float* __restrict__ out, const int* __restrict__ batch) {
    int g = blockIdx.x;
    int lane = threadIdx.x;
    int lo = 0, hi = N_NODES;
    while (lo < hi) { int m = (lo + hi) >> 1; if (batch[m] < g) lo = m + 1; else hi = m; }
    int start = lo;
    hi = N_NODES;
    while (lo < hi) { int m = (lo + hi) >> 1; if (batch[m] < g + 1) lo = m + 1; else hi = m; }
    float c = (float)(lo - start);
    out[g * D + lane] /= fmaxf(c, 1.0f);
}

// ---------------- launch ----------------
extern "C" void kernel_launch(void* const* d_in, const int* in_sizes, int n_in,
                              void* d_out, int out_size, void* d_ws, size_t ws_size,
                              hipStream_t stream) {
    const float* x     = (const float*)d_in[0];
    const int*   ei    = (const int*)d_in[1];
    const int*   src   = ei;
    const int*   dst   = ei + N_EDGES;
    const int*   batch = (const int*)d_in[2];
    const float* ew    = (const float*)d_in[3];
    const float* W1    = (const float*)d_in[4];
    const float* b1    = (const float*)d_in[5];
    const float* W2    = (const float*)d_in[6];
    const float* b2    = (const float*)d_in[7];
    float* out = (float*)d_out;

    char* ws = (char*)d_ws;
    __half* xh     = (__half*)(ws);                               // 12.8 MB
    __half* hh     = (__half*)(ws + 12800000);                    // 12.8 MB
    float2* csr    = (float2*)(ws + 25600000);                    // 12.8 MB
    unsigned long long* deg64 = (unsigned long long*)(ws + 38400000); // 800 KB
    float*  dinv   = (float*)(ws + 39200000);                     // 400 KB
    int*    rowptr = (int*)(ws + 39600000);                       // 400 KB
    int*    cursor = (int*)(ws + 40000000);                       // 400 KB
    int*    cnt    = (int*)(ws + 40400000);                       // 400 KB
    int*    bsums  = (int*)(ws + 40800000);                       // 2 KB

    // zero-init via async memset
    hipMemsetAsync(deg64, 0, N_NODES * sizeof(unsigned long long), stream);
    hipMemsetAsync(out, 0, N_GRAPHS * D * sizeof(float), stream);

    // fp16 conversion of x (independent of everything else)
    k_half<<<2048, 256, 0, stream>>>(x, xh);
    // packed degree+count: 1 atomic per edge
    k_count_deg<<<(N_EDGES / 4 + 255) / 256, 256, 0, stream>>>(
        (const int4*)dst, (const float4*)ew, deg64);
    k_scan1<<<NBLK, 256, 0, stream>>>(deg64, rowptr, bsums, dinv);
    k_scan2<<<1, 512, 0, stream>>>(bsums);
    k_scan3<<<NBLK, 256, 0, stream>>>(rowptr, deg64, bsums, rowptr, cursor, cnt);
    k_scatter<<<(N_EDGES / 4 + 255) / 256, 256, 0, stream>>>(
        (const int4*)src, (const int4*)dst, (const float4*)ew, dinv, cursor, csr);

    // layer 1: hh = fp16(relu((A xh) W1 + b1))
    k_layer<1><<<2048, 256, 0, stream>>>(xh, W1, b1, dinv, rowptr, cnt, csr, batch, hh, out);
    // layer 2 + pool-sum: out[g] += relu((A hh) W2 + b2)
    k_layer<2><<<2048, 256, 0, stream>>>(hh, W2, b2, dinv, rowptr, cnt, csr, batch, hh, out);
    // mean
    k_finalize<<<N_GRAPHS, D, 0, stream>>>(out, batch);
}

// Round 20
// 419.242 us; speedup vs baseline: 1.1402x; 1.1402x over previous
//
#include <hip/hip_runtime.h>
#include <hip/hip_fp16.h>

#define N_NODES 100000
#define N_EDGES 1600000
#define D 64
#define N_GRAPHS 64
#define NBLK ((N_NODES + 255) / 256)   // 391 scan blocks
#define WTS 68                         // WT row stride (floats): conflict-free

// ---------------- packed degree + count: ONE uint64 atomic per edge ---------
// deg64[d] += (1<<40) | round(ew * 2^20): upper bits = edge count, low 40 =
// fixed-point weight sum (max sum ~60 << 2^20 capacity; err <= 5e-7/edge).
__global__ void k_count_deg(const int4* __restrict__ dst4,
                            const float4* __restrict__ ew4,
                            unsigned long long* __restrict__ deg64) {
    int e4 = blockIdx.x * blockDim.x + threadIdx.x;
    if (e4 < N_EDGES / 4) {
        int4   d = dst4[e4];
        float4 w = ew4[e4];
        const float s = 1048576.0f;   // 2^20
        atomicAdd(&deg64[d.x], (1ULL << 40) + (unsigned long long)(w.x * s + 0.5f));
        atomicAdd(&deg64[d.y], (1ULL << 40) + (unsigned long long)(w.y * s + 0.5f));
        atomicAdd(&deg64[d.z], (1ULL << 40) + (unsigned long long)(w.z * s + 0.5f));
        atomicAdd(&deg64[d.w], (1ULL << 40) + (unsigned long long)(w.w * s + 0.5f));
    }
}

// ---------------- unpack dinv + exclusive scan of cnt -> partial ------------
__global__ void k_scan1(const unsigned long long* __restrict__ deg64,
                        int* __restrict__ partial, int* __restrict__ bsums,
                        float* __restrict__ dinv) {
    int t = threadIdx.x, b = blockIdx.x, i = b * 256 + t;
    int v = 0;
    if (i < N_NODES) {
        unsigned long long pk = deg64[i];
        v = (int)(pk >> 40);
        float degf = (float)(pk & ((1ULL << 40) - 1)) * (1.0f / 1048576.0f);
        dinv[i] = rsqrtf(degf + 1.0f);   // + self-loop weight 1
    }
    int incl = v;
    int lane = t & 63;
#pragma unroll
    for (int off = 1; off < 64; off <<= 1) {
        int u = __shfl_up(incl, off);
        if (lane >= off) incl += u;
    }
    __shared__ int wsum[4];
    int w = t >> 6;
    if (lane == 63) wsum[w] = incl;
    __syncthreads();
    int add = 0;
    for (int k = 0; k < w; ++k) add += wsum[k];
    incl += add;
    if (i < N_NODES) partial[i] = incl;
    if (t == 255) bsums[b] = incl;
}

__global__ void k_scan2(int* __restrict__ bsums) {
    __shared__ int s[512];
    int t = threadIdx.x;
    s[t] = (t < NBLK) ? bsums[t] : 0;
    __syncthreads();
    for (int off = 1; off < 512; off <<= 1) {
        int u = (t >= off) ? s[t - off] : 0;
        __syncthreads();
        s[t] += u;
        __syncthreads();
    }
    if (t < NBLK) bsums[t] = (t == 0) ? 0 : s[t - 1];  // exclusive
}

// rowptr gets N_NODES+1 entries so k_layer derives dg = rowptr[i+1]-rowptr[i]
__global__ void k_scan3(const int* __restrict__ partial,
                        const unsigned long long* __restrict__ deg64,
                        const int* __restrict__ bsums, int* __restrict__ rowptr,
                        int* __restrict__ cursor) {
    int i = blockIdx.x * 256 + threadIdx.x;
    if (i < N_NODES) {
        int cnt = (int)(deg64[i] >> 40);
        int excl = partial[i] - cnt + bsums[blockIdx.x];
        rowptr[i] = excl;
        cursor[i] = excl;
        if (i == N_NODES - 1) rowptr[N_NODES] = excl + cnt;
    }
}

// ---------------- scatter edges into CSR (src, norm) grouped by dst ----------
__global__ void k_scatter(const int* __restrict__ src, const int* __restrict__ dst,
                          const float* __restrict__ ew, const float* __restrict__ dinv,
                          int* __restrict__ cursor, float2* __restrict__ csr) {
    int e = blockIdx.x * blockDim.x + threadIdx.x;
    if (e < N_EDGES) {
        int s = src[e];
        int d = dst[e];
        float nrm = dinv[s] * ew[e] * dinv[d];   // dinv table 400KB: L2-resident
        int pos = atomicAdd(&cursor[d], 1);
        csr[pos] = make_float2(__int_as_float(s), nrm);
    }
}

// ---------------- x -> fp16 table [N][64] ----------------
__global__ void k_half(const float* __restrict__ x, __half* __restrict__ xh) {
    int i = blockIdx.x * blockDim.x + threadIdx.x;
    const int total = N_NODES * D / 4;
    const int stride = gridDim.x * blockDim.x;
    const float4* x4 = (const float4*)x;
    __half2* xh2 = (__half2*)xh;
    for (; i < total; i += stride) {
        float4 v = x4[i];
        xh2[2 * i + 0] = __floats2half2_rn(v.x, v.y);
        xh2[2 * i + 1] = __floats2half2_rn(v.z, v.w);
    }
}

// ---------------- fused layer: fp16 table + float4-grouped gathers ----------
// Best-measured layer kernel (r16/r18): fp16 halves bytes/edge AND slot/q
// grouping quarters gather instructions — the only dual relief that moved the
// L2-miss-bound gather wall (falsified vs bytes, instrs, waves, scheduling,
// ILP, placement, re-association across rounds 7-17).
// lane = (slot in [0,4))*16 + q. Per 16-edge pass: 1 csr load + 8 shfl +
// 4 uint2 gathers (each covers 4 fp16 rows, 512 B). Slot-fold: 8 shfl_xor.
// GEMM f32 (transposed-W LDS, stride 68).
// LAYER==1: store row as fp16 (next table). LAYER==2: f32 pool-atomicAdd.
template <int LAYER>
__global__ __launch_bounds__(256) void k_layer(
        const __half* __restrict__ in, const float* __restrict__ W,
        const float* __restrict__ bias, const float* __restrict__ dinv,
        const int* __restrict__ rowptr, const int* __restrict__ batch,
        const float2* __restrict__ csr,
        __half* __restrict__ outh, float* __restrict__ outf) {
    __shared__ float WTs[D * WTS];       // 17408 B transposed W
    __shared__ float aw[4][D];           // per-wave row staging
    __shared__ float bs[D];

    {   // stage W transposed: WTs[c*WTS + k] = W[k*D + c]
        int t = threadIdx.x;
#pragma unroll
        for (int i = 0; i < 16; ++i) {
            int idx = t + i * 256;
            int k = idx >> 6, c = idx & 63;
            WTs[c * WTS + k] = W[idx];
        }
        if (t < D) bs[t] = bias[t];
    }
    __syncthreads();

    const int lane = threadIdx.x & 63;
    const int wid  = threadIdx.x >> 6;
    const int slot = lane >> 4;          // 0..3
    const int q    = lane & 15;          // 0..15
    float* awm = aw[wid];
    const float bl = bs[lane];
    const uint2* in2 = (const uint2*)in; // row i = in2[i*16 .. i*16+15]

    int gw = (blockIdx.x * blockDim.x + threadIdx.x) >> 6;
    const int tw = (gridDim.x * blockDim.x) >> 6;

    for (int row = gw; row < N_NODES; row += tw) {
        const int st = __builtin_amdgcn_readfirstlane(rowptr[row]);
        const int en = __builtin_amdgcn_readfirstlane(rowptr[row + 1]);
        const int dg = en - st;
        const int cl = dg > 0 ? dg - 1 : 0;   // clamp index (safe for dg==0)

        float4 acc = make_float4(0.f, 0.f, 0.f, 0.f);
        {   // self-loop on slot 0
            if (slot == 0) {
                float di = dinv[row];
                float d2 = di * di;
                uint2 v = in2[row * 16 + q];
                float2 f0 = __half22float2(*(__half2*)&v.x);
                float2 f1 = __half22float2(*(__half2*)&v.y);
                acc.x = f0.x * d2; acc.y = f0.y * d2;
                acc.z = f1.x * d2; acc.w = f1.y * d2;
            }
        }

        for (int j = 0; j < dg; j += 16) {
            // one per-lane csr load covers 16 edges (4x slot redundancy)
            int ie = j + q;
            float2 c = csr[st + (ie < cl ? ie : cl)];
            // distribute: slot handles edges j+4k+slot (entry in lane 4k+slot)
            float sx0 = __shfl(c.x, 4 * 0 + slot);
            float wv0 = __shfl(c.y, 4 * 0 + slot);
            float sx1 = __shfl(c.x, 4 * 1 + slot);
            float wv1 = __shfl(c.y, 4 * 1 + slot);
            float sx2 = __shfl(c.x, 4 * 2 + slot);
            float wv2 = __shfl(c.y, 4 * 2 + slot);
            float sx3 = __shfl(c.x, 4 * 3 + slot);
            float wv3 = __shfl(c.y, 4 * 3 + slot);
            wv0 = (j + 0  + slot < dg) ? wv0 : 0.f;
            wv1 = (j + 4  + slot < dg) ? wv1 : 0.f;
            wv2 = (j + 8  + slot < dg) ? wv2 : 0.f;
            wv3 = (j + 12 + slot < dg) ? wv3 : 0.f;
            int i0 = __float_as_int(sx0);
            int i1 = __float_as_int(sx1);
            int i2 = __float_as_int(sx2);
            int i3 = __float_as_int(sx3);
            // 4 uint2 gathers: each instruction covers 4 fp16 rows (512 B)
            uint2 v0 = in2[i0 * 16 + q];
            uint2 v1 = in2[i1 * 16 + q];
            uint2 v2 = in2[i2 * 16 + q];
            uint2 v3 = in2[i3 * 16 + q];
            {
                float2 f0 = __half22float2(*(__half2*)&v0.x);
                float2 f1 = __half22float2(*(__half2*)&v0.y);
                acc.x = fmaf(f0.x, wv0, acc.x); acc.y = fmaf(f0.y, wv0, acc.y);
                acc.z = fmaf(f1.x, wv0, acc.z); acc.w = fmaf(f1.y, wv0, acc.w);
            }
            {
                float2 f0 = __half22float2(*(__half2*)&v1.x);
                float2 f1 = __half22float2(*(__half2*)&v1.y);
                acc.x = fmaf(f0.x, wv1, acc.x); acc.y = fmaf(f0.y, wv1, acc.y);
                acc.z = fmaf(f1.x, wv1, acc.z); acc.w = fmaf(f1.y, wv1, acc.w);
            }
            {
                float2 f0 = __half22float2(*(__half2*)&v2.x);
                float2 f1 = __half22float2(*(__half2*)&v2.y);
                acc.x = fmaf(f0.x, wv2, acc.x); acc.y = fmaf(f0.y, wv2, acc.y);
                acc.z = fmaf(f1.x, wv2, acc.z); acc.w = fmaf(f1.y, wv2, acc.w);
            }
            {
                float2 f0 = __half22float2(*(__half2*)&v3.x);
                float2 f1 = __half22float2(*(__half2*)&v3.y);
                acc.x = fmaf(f0.x, wv3, acc.x); acc.y = fmaf(f0.y, wv3, acc.y);
                acc.z = fmaf(f1.x, wv3, acc.z); acc.w = fmaf(f1.y, wv3, acc.w);
            }
        }

        // fold the 4 slots (same q): slot 0 ends with the row
        acc.x += __shfl_xor(acc.x, 16); acc.y += __shfl_xor(acc.y, 16);
        acc.z += __shfl_xor(acc.z, 16); acc.w += __shfl_xor(acc.w, 16);
        acc.x += __shfl_xor(acc.x, 32); acc.y += __shfl_xor(acc.y, 32);
        acc.z += __shfl_xor(acc.z, 32); acc.w += __shfl_xor(acc.w, 32);
        if (slot == 0) *(float4*)&awm[q * 4] = acc;
        // same-wave LDS RAW: in-order LDS pipe, no barrier needed

        // ---- GEMM: r[lane] = sum_k aw[k] * W[k][lane] ----
        float r0 = 0.f, r1 = 0.f, r2 = 0.f, r3 = 0.f;
#pragma unroll
        for (int t = 0; t < 16; ++t) {
            float4 a = *(const float4*)&awm[t * 4];                // broadcast
            float4 w = *(const float4*)&WTs[lane * WTS + t * 4];   // conflict-free
            r0 = fmaf(a.x, w.x, r0);
            r1 = fmaf(a.y, w.y, r1);
            r2 = fmaf(a.z, w.z, r2);
            r3 = fmaf(a.w, w.w, r3);
        }
        float r = fmaxf((r0 + r1) + (r2 + r3) + bl, 0.f);

        if (LAYER == 1) {
            outh[row * D + lane] = __float2half_rn(r);   // fp16 table for L2
        } else {
            atomicAdd(&outf[batch[row] * D + lane], r);
        }
    }
}

// ---------------- finalize pool: divide by per-graph node count ----------------
__global__ void k_finalize(float* __restrict__ out, const int* __restrict__ batch) {
    int g = blockIdx.x;
    int lane = threadIdx.x;
    int lo = 0, hi = N_NODES;
    while (lo < hi) { int m = (lo + hi) >> 1; if (batch[m] < g) lo = m + 1; else hi = m; }
    int start = lo;
    hi = N_NODES;
    while (lo < hi) { int m = (lo + hi) >> 1; if (batch[m] < g + 1) lo = m + 1; else hi = m; }
    float c = (float)(lo - start);
    out[g * D + lane] /= fmaxf(c, 1.0f);
}

// ---------------- launch ----------------
extern "C" void kernel_launch(void* const* d_in, const int* in_sizes, int n_in,
                              void* d_out, int out_size, void* d_ws, size_t ws_size,
                              hipStream_t stream) {
    const float* x     = (const float*)d_in[0];
    const int*   ei    = (const int*)d_in[1];
    const int*   src   = ei;
    const int*   dst   = ei + N_EDGES;
    const int*   batch = (const int*)d_in[2];
    const float* ew    = (const float*)d_in[3];
    const float* W1    = (const float*)d_in[4];
    const float* b1    = (const float*)d_in[5];
    const float* W2    = (const float*)d_in[6];
    const float* b2    = (const float*)d_in[7];
    float* out = (float*)d_out;

    char* ws = (char*)d_ws;
    __half* xh     = (__half*)(ws);                               // 12.8 MB
    __half* hh     = (__half*)(ws + 12800000);                    // 12.8 MB
    float2* csr    = (float2*)(ws + 25600000);                    // 12.8 MB
    unsigned long long* deg64 = (unsigned long long*)(ws + 38400000); // 800 KB
    float*  dinv   = (float*)(ws + 39200000);                     // 400 KB
    int*    rowptr = (int*)(ws + 39600000);                       // 400 KB + 4
    int*    cursor = (int*)(ws + 40000016);                       // 400 KB
    int*    bsums  = (int*)(ws + 40400016);                       // 2 KB

    // zero-init via async memset
    hipMemsetAsync(deg64, 0, N_NODES * sizeof(unsigned long long), stream);
    hipMemsetAsync(out, 0, N_GRAPHS * D * sizeof(float), stream);

    // fp16 conversion of x (independent of everything else)
    k_half<<<1024, 256, 0, stream>>>(x, xh);
    // packed degree+count: 1 atomic per edge
    k_count_deg<<<(N_EDGES / 4 + 255) / 256, 256, 0, stream>>>(
        (const int4*)dst, (const float4*)ew, deg64);
    k_scan1<<<NBLK, 256, 0, stream>>>(deg64, rowptr, bsums, dinv);
    k_scan2<<<1, 512, 0, stream>>>(bsums);
    k_scan3<<<NBLK, 256, 0, stream>>>(rowptr, deg64, bsums, rowptr, cursor);
    k_scatter<<<(N_EDGES + 255) / 256, 256, 0, stream>>>(src, dst, ew, dinv, cursor, csr);

    // layer 1: hh = fp16(relu((A xh) W1 + b1))
    k_layer<1><<<2048, 256, 0, stream>>>(xh, W1, b1, dinv, rowptr, batch, csr, hh, out);
    // layer 2 + pool-sum: out[g] += relu((A hh) W2 + b2)
    k_layer<2><<<2048, 256, 0, stream>>>(hh, W2, b2, dinv, rowptr, batch, csr, hh, out);
    // mean
    k_finalize<<<N_GRAPHS, D, 0, stream>>>(out, batch);
}